// Round 2
// baseline (1578.042 us; speedup 1.0000x reference)
//
#include <hip/hip_runtime.h>
#include <hip/hip_bf16.h>

#define AN 100000
#define BN 200000
#define MN 50000
#define HD 128
#define NMOL 4000
#define MAXNB 8

typedef unsigned short u16;
typedef unsigned int   u32;

__device__ __forceinline__ u16 f2bf(float x) {
    u32 u = __float_as_uint(x);
    return (u16)((u + 0x7fffu + ((u >> 16) & 1u)) >> 16);
}

// ---------------- k_binput: g0 = relu(fbonds @ W_i) as bf16 ------------------
__global__ __launch_bounds__(256) void k_binput(const float* __restrict__ fbonds,
                                                const float* __restrict__ W_i,
                                                u16* __restrict__ g0) {
    __shared__ float sW[40 * HD];       // 20.5 KB
    __shared__ float sfb[16][40];
    int tid = threadIdx.x;
    int b0  = blockIdx.x * 16;
    for (int i = tid; i < 40 * HD; i += 256) sW[i] = W_i[i];
    for (int i = tid; i < 16 * 40; i += 256) {
        int t = i / 40, k = i % 40;
        sfb[t][k] = fbonds[(size_t)(b0 + t) * 40 + k];
    }
    __syncthreads();
    int c  = tid & 127;
    int th = tid >> 7;
#pragma unroll
    for (int q = 0; q < 8; ++q) {
        int t = th + 2 * q;
        float acc = 0.f;
#pragma unroll
        for (int k = 0; k < 40; ++k) acc = fmaf(sfb[t][k], sW[k * HD + c], acc);
        g0[(size_t)(b0 + t) * HD + c] = f2bf(fmaxf(acc, 0.f));
    }
}

// ------- k_iter: tout = relu(fbonds@W_i + (sum_j msg[bgraph]) @ W_h) bf16 ----
__global__ __launch_bounds__(256) void k_iter(const float* __restrict__ tree,
                                              const u16* __restrict__ tin,
                                              const float* __restrict__ fbonds,
                                              const int* __restrict__ bgraph,
                                              const float* __restrict__ W_h,
                                              const float* __restrict__ W_i,
                                              u16* __restrict__ tout) {
    __shared__ float nei[16][HD];       // 8 KB
    __shared__ float sfb[16][40];
    __shared__ int   sidx[16][MAXNB];
    int tid = threadIdx.x;
    int b0  = blockIdx.x * 16;

    if (tid < 128) {
        int t = tid >> 3, j = tid & 7;
        sidx[t][j] = bgraph[(size_t)(b0 + t) * MAXNB + j];
    }
    for (int i = tid; i < 16 * 40; i += 256) {
        int t = i / 40, k = i % 40;
        sfb[t][k] = fbonds[(size_t)(b0 + t) * 40 + k];
    }
    __syncthreads();

    // gather: 16 lanes/bond, lane covers 8 consecutive elements
    {
        int t = tid >> 4;
        int l = tid & 15;
        float a[8] = {0.f, 0.f, 0.f, 0.f, 0.f, 0.f, 0.f, 0.f};
#pragma unroll
        for (int j = 0; j < MAXNB; ++j) {
            int idx = sidx[t][j];
            if (idx < MN) {
                const float4* r4 = (const float4*)(tree + (size_t)idx * HD);
                float4 v0 = r4[2 * l], v1 = r4[2 * l + 1];
                a[0] += v0.x; a[1] += v0.y; a[2] += v0.z; a[3] += v0.w;
                a[4] += v1.x; a[5] += v1.y; a[6] += v1.z; a[7] += v1.w;
            } else {
                const uint4* r4 = (const uint4*)(tin + (size_t)(idx - MN) * HD);
                uint4 v = r4[l];
                a[0] += __uint_as_float(v.x << 16);
                a[1] += __uint_as_float(v.x & 0xffff0000u);
                a[2] += __uint_as_float(v.y << 16);
                a[3] += __uint_as_float(v.y & 0xffff0000u);
                a[4] += __uint_as_float(v.z << 16);
                a[5] += __uint_as_float(v.z & 0xffff0000u);
                a[6] += __uint_as_float(v.w << 16);
                a[7] += __uint_as_float(v.w & 0xffff0000u);
            }
        }
        float4* n4 = (float4*)nei[t];
        n4[2 * l]     = make_float4(a[0], a[1], a[2], a[3]);
        n4[2 * l + 1] = make_float4(a[4], a[5], a[6], a[7]);
    }
    __syncthreads();

    // GEMM: 32 col-threads x 8 bond-threads, 2 bonds x 4 cols each
    int ct = tid & 31;
    int bt = tid >> 5;
    float acc[2][4] = {{0.f, 0.f, 0.f, 0.f}, {0.f, 0.f, 0.f, 0.f}};
    const float4* W4 = (const float4*)W_h;
    for (int k = 0; k < HD; k += 4) {
        float4 a0 = *(const float4*)&nei[bt][k];
        float4 a1 = *(const float4*)&nei[bt + 8][k];
#pragma unroll
        for (int kk = 0; kk < 4; ++kk) {
            float4 w = W4[(k + kk) * 32 + ct];
            float av0 = ((const float*)&a0)[kk];
            float av1 = ((const float*)&a1)[kk];
            acc[0][0] = fmaf(av0, w.x, acc[0][0]);
            acc[0][1] = fmaf(av0, w.y, acc[0][1]);
            acc[0][2] = fmaf(av0, w.z, acc[0][2]);
            acc[0][3] = fmaf(av0, w.w, acc[0][3]);
            acc[1][0] = fmaf(av1, w.x, acc[1][0]);
            acc[1][1] = fmaf(av1, w.y, acc[1][1]);
            acc[1][2] = fmaf(av1, w.z, acc[1][2]);
            acc[1][3] = fmaf(av1, w.w, acc[1][3]);
        }
    }
    // recomputed binput contribution: fbonds(40) @ W_i
    const float4* Wi4 = (const float4*)W_i;
    for (int k = 0; k < 40; ++k) {
        float4 w = Wi4[k * 32 + ct];
        float f0 = sfb[bt][k];
        float f1 = sfb[bt + 8][k];
        acc[0][0] = fmaf(f0, w.x, acc[0][0]);
        acc[0][1] = fmaf(f0, w.y, acc[0][1]);
        acc[0][2] = fmaf(f0, w.z, acc[0][2]);
        acc[0][3] = fmaf(f0, w.w, acc[0][3]);
        acc[1][0] = fmaf(f1, w.x, acc[1][0]);
        acc[1][1] = fmaf(f1, w.y, acc[1][1]);
        acc[1][2] = fmaf(f1, w.z, acc[1][2]);
        acc[1][3] = fmaf(f1, w.w, acc[1][3]);
    }
#pragma unroll
    for (int t2 = 0; t2 < 2; ++t2) {
        size_t b = (size_t)b0 + bt + 8 * t2;
        uint2 r;
        r.x = (u32)f2bf(fmaxf(acc[t2][0], 0.f)) | ((u32)f2bf(fmaxf(acc[t2][1], 0.f)) << 16);
        r.y = (u32)f2bf(fmaxf(acc[t2][2], 0.f)) | ((u32)f2bf(fmaxf(acc[t2][3], 0.f)) << 16);
        ((uint2*)(tout + b * HD))[ct] = r;
    }
}

// ---------------- k_atom: atom_hiddens -> atomic segment sums ----------------
__global__ __launch_bounds__(256) void k_atom(const float* __restrict__ tree,
                                              const u16* __restrict__ gfin,
                                              const float* __restrict__ fatoms,
                                              const int* __restrict__ agraph,
                                              const int* __restrict__ mol_id,
                                              const float* __restrict__ W_o,
                                              const float* __restrict__ b_o,
                                              float* __restrict__ sums) {
    __shared__ float nei[16][HD];
    __shared__ float sfat[16][36];
    __shared__ int   sidx[16][MAXNB];
    int tid = threadIdx.x;
    int a0  = blockIdx.x * 16;

    if (tid < 128) {
        int t = tid >> 3, j = tid & 7;
        sidx[t][j] = agraph[(size_t)(a0 + t) * MAXNB + j];
    }
    for (int i = tid; i < 16 * 35; i += 256) {
        int t = i / 35, k = i % 35;
        sfat[t][k] = fatoms[(size_t)(a0 + t) * 35 + k];
    }
    __syncthreads();

    {
        int t = tid >> 4;
        int l = tid & 15;
        float a[8] = {0.f, 0.f, 0.f, 0.f, 0.f, 0.f, 0.f, 0.f};
#pragma unroll
        for (int j = 0; j < MAXNB; ++j) {
            int idx = sidx[t][j];
            if (idx < MN) {
                const float4* r4 = (const float4*)(tree + (size_t)idx * HD);
                float4 v0 = r4[2 * l], v1 = r4[2 * l + 1];
                a[0] += v0.x; a[1] += v0.y; a[2] += v0.z; a[3] += v0.w;
                a[4] += v1.x; a[5] += v1.y; a[6] += v1.z; a[7] += v1.w;
            } else {
                const uint4* r4 = (const uint4*)(gfin + (size_t)(idx - MN) * HD);
                uint4 v = r4[l];
                a[0] += __uint_as_float(v.x << 16);
                a[1] += __uint_as_float(v.x & 0xffff0000u);
                a[2] += __uint_as_float(v.y << 16);
                a[3] += __uint_as_float(v.y & 0xffff0000u);
                a[4] += __uint_as_float(v.z << 16);
                a[5] += __uint_as_float(v.z & 0xffff0000u);
                a[6] += __uint_as_float(v.w << 16);
                a[7] += __uint_as_float(v.w & 0xffff0000u);
            }
        }
        float4* n4 = (float4*)nei[t];
        n4[2 * l]     = make_float4(a[0], a[1], a[2], a[3]);
        n4[2 * l + 1] = make_float4(a[4], a[5], a[6], a[7]);
    }
    __syncthreads();

    int ct = tid & 31;
    int bt = tid >> 5;
    float4 bo = ((const float4*)b_o)[ct];
    float acc[2][4] = {{bo.x, bo.y, bo.z, bo.w}, {bo.x, bo.y, bo.z, bo.w}};
    const float4* W4 = (const float4*)(W_o + 35 * HD);   // rows 35..162
    for (int k = 0; k < HD; k += 4) {
        float4 a0v = *(const float4*)&nei[bt][k];
        float4 a1v = *(const float4*)&nei[bt + 8][k];
#pragma unroll
        for (int kk = 0; kk < 4; ++kk) {
            float4 w = W4[(k + kk) * 32 + ct];
            float av0 = ((const float*)&a0v)[kk];
            float av1 = ((const float*)&a1v)[kk];
            acc[0][0] = fmaf(av0, w.x, acc[0][0]);
            acc[0][1] = fmaf(av0, w.y, acc[0][1]);
            acc[0][2] = fmaf(av0, w.z, acc[0][2]);
            acc[0][3] = fmaf(av0, w.w, acc[0][3]);
            acc[1][0] = fmaf(av1, w.x, acc[1][0]);
            acc[1][1] = fmaf(av1, w.y, acc[1][1]);
            acc[1][2] = fmaf(av1, w.z, acc[1][2]);
            acc[1][3] = fmaf(av1, w.w, acc[1][3]);
        }
    }
    const float4* W4a = (const float4*)W_o;              // rows 0..34
    for (int k = 0; k < 35; ++k) {
        float4 w = W4a[k * 32 + ct];
        float f0 = sfat[bt][k];
        float f1 = sfat[bt + 8][k];
        acc[0][0] = fmaf(f0, w.x, acc[0][0]);
        acc[0][1] = fmaf(f0, w.y, acc[0][1]);
        acc[0][2] = fmaf(f0, w.z, acc[0][2]);
        acc[0][3] = fmaf(f0, w.w, acc[0][3]);
        acc[1][0] = fmaf(f1, w.x, acc[1][0]);
        acc[1][1] = fmaf(f1, w.y, acc[1][1]);
        acc[1][2] = fmaf(f1, w.z, acc[1][2]);
        acc[1][3] = fmaf(f1, w.w, acc[1][3]);
    }
#pragma unroll
    for (int t2 = 0; t2 < 2; ++t2) {
        int a = a0 + bt + 8 * t2;
        int m = mol_id[a];
        float* dst = sums + (size_t)m * HD + 4 * ct;
        atomicAdd(dst + 0, fmaxf(acc[t2][0], 0.f));
        atomicAdd(dst + 1, fmaxf(acc[t2][1], 0.f));
        atomicAdd(dst + 2, fmaxf(acc[t2][2], 0.f));
        atomicAdd(dst + 3, fmaxf(acc[t2][3], 0.f));
    }
}

// ---------------- k_counts / k_div -------------------------------------------
__global__ __launch_bounds__(256) void k_counts(const int* __restrict__ mol_id,
                                                float* __restrict__ counts) {
    int a = blockIdx.x * 256 + threadIdx.x;
    if (a < AN) atomicAdd(&counts[mol_id[a]], 1.f);
}

__global__ __launch_bounds__(256) void k_div(const float* __restrict__ sums,
                                             const float* __restrict__ counts,
                                             float* __restrict__ out) {
    int i = blockIdx.x * 256 + threadIdx.x;
    if (i < NMOL * HD) out[i] = sums[i] / fmaxf(counts[i >> 7], 1.f);
}

extern "C" void kernel_launch(void* const* d_in, const int* in_sizes, int n_in,
                              void* d_out, int out_size, void* d_ws, size_t ws_size,
                              hipStream_t stream) {
    const float* fatoms = (const float*)d_in[0];
    const float* fbonds = (const float*)d_in[1];
    const float* tree   = (const float*)d_in[2];
    const int*   agraph = (const int*)d_in[3];
    const int*   bgraph = (const int*)d_in[4];
    const int*   mol_id = (const int*)d_in[5];
    const float* W_i    = (const float*)d_in[6];
    const float* W_h    = (const float*)d_in[7];
    const float* W_o    = (const float*)d_in[8];
    const float* b_o    = (const float*)d_in[9];
    float* out = (float*)d_out;

    // workspace: t0 (51.2MB bf16) | t1 (51.2MB bf16) | sums (2.05MB) | counts
    u16*   t0     = (u16*)d_ws;
    u16*   t1     = t0 + (size_t)BN * HD;
    float* sums   = (float*)(t1 + (size_t)BN * HD);
    float* counts = sums + (size_t)NMOL * HD;

    hipMemsetAsync(sums, 0, (size_t)(NMOL * HD + NMOL) * sizeof(float), stream);

    k_binput<<<BN / 16, 256, 0, stream>>>(fbonds, W_i, t0);

    u16* cur = t0;
    u16* nxt = t1;
    for (int it = 0; it < 4; ++it) {
        k_iter<<<BN / 16, 256, 0, stream>>>(tree, cur, fbonds, bgraph, W_h, W_i, nxt);
        u16* t = cur; cur = nxt; nxt = t;
    }

    k_counts<<<(AN + 255) / 256, 256, 0, stream>>>(mol_id, counts);
    k_atom<<<AN / 16, 256, 0, stream>>>(tree, cur, fatoms, agraph, mol_id, W_o, b_o, sums);
    k_div<<<(NMOL * HD) / 256, 256, 0, stream>>>(sums, counts, out);
}

// Round 3
// 1536.473 us; speedup vs baseline: 1.0271x; 1.0271x over previous
//
#include <hip/hip_runtime.h>
#include <hip/hip_bf16.h>

#define AN 100000
#define BN 200000
#define MN 50000
#define HD 128
#define NMOL 4000
#define MAXNB 8

typedef unsigned short u16;
typedef unsigned int   u32;

__device__ __forceinline__ u16 f2bf(float x) {
    u32 u = __float_as_uint(x);
    return (u16)((u + 0x7fffu + ((u >> 16) & 1u)) >> 16);
}

// ---------------- k_tree: tree fp32 -> bf16 table ----------------------------
__global__ __launch_bounds__(256) void k_tree(const float* __restrict__ tree,
                                              u16* __restrict__ tree_bf) {
    int i = blockIdx.x * 256 + threadIdx.x;       // one float4 per thread
    const float4 v = ((const float4*)tree)[i];
    uint2 r;
    r.x = (u32)f2bf(v.x) | ((u32)f2bf(v.y) << 16);
    r.y = (u32)f2bf(v.z) | ((u32)f2bf(v.w) << 16);
    ((uint2*)tree_bf)[i] = r;
}

// ---------------- k_binput: g0 = relu(fbonds @ W_i) as bf16 ------------------
__global__ __launch_bounds__(256) void k_binput(const float* __restrict__ fbonds,
                                                const float* __restrict__ W_i,
                                                u16* __restrict__ g0) {
    __shared__ float sW[40 * HD];
    __shared__ float sfb[16][40];
    int tid = threadIdx.x;
    int b0  = blockIdx.x * 16;
    for (int i = tid; i < 40 * HD; i += 256) sW[i] = W_i[i];
    for (int i = tid; i < 16 * 40; i += 256) {
        int t = i / 40, k = i % 40;
        sfb[t][k] = fbonds[(size_t)(b0 + t) * 40 + k];
    }
    __syncthreads();
    int c  = tid & 127;
    int th = tid >> 7;
#pragma unroll
    for (int q = 0; q < 8; ++q) {
        int t = th + 2 * q;
        float acc = 0.f;
#pragma unroll
        for (int k = 0; k < 40; ++k) acc = fmaf(sfb[t][k], sW[k * HD + c], acc);
        g0[(size_t)(b0 + t) * HD + c] = f2bf(fmaxf(acc, 0.f));
    }
}

// ---- shared gather helper: branchless, 8 loads in flight --------------------
template <bool UNIFIED>
__device__ __forceinline__ void gather_row(const float* __restrict__ tree,
                                           const u16* __restrict__ tree_bf,
                                           const u16* __restrict__ tin,
                                           const int* sidx_t, int l,
                                           float* __restrict__ a /*[8]*/) {
#pragma unroll
    for (int q = 0; q < 8; ++q) a[q] = 0.f;
    if (UNIFIED) {
        uint4 v[MAXNB];
#pragma unroll
        for (int j = 0; j < MAXNB; ++j) {
            int idx = sidx_t[j];
            const u16* base = (idx < MN) ? (tree_bf + (size_t)idx * HD)
                                         : (tin + (size_t)(idx - MN) * HD);
            v[j] = ((const uint4*)base)[l];
        }
#pragma unroll
        for (int j = 0; j < MAXNB; ++j) {
            a[0] += __uint_as_float(v[j].x << 16);
            a[1] += __uint_as_float(v[j].x & 0xffff0000u);
            a[2] += __uint_as_float(v[j].y << 16);
            a[3] += __uint_as_float(v[j].y & 0xffff0000u);
            a[4] += __uint_as_float(v[j].z << 16);
            a[5] += __uint_as_float(v[j].z & 0xffff0000u);
            a[6] += __uint_as_float(v[j].w << 16);
            a[7] += __uint_as_float(v[j].w & 0xffff0000u);
        }
    } else {
#pragma unroll
        for (int j = 0; j < MAXNB; ++j) {
            int idx = sidx_t[j];
            if (idx < MN) {
                const float4* r4 = (const float4*)(tree + (size_t)idx * HD);
                float4 v0 = r4[2 * l], v1 = r4[2 * l + 1];
                a[0] += v0.x; a[1] += v0.y; a[2] += v0.z; a[3] += v0.w;
                a[4] += v1.x; a[5] += v1.y; a[6] += v1.z; a[7] += v1.w;
            } else {
                const uint4* r4 = (const uint4*)(tin + (size_t)(idx - MN) * HD);
                uint4 v = r4[l];
                a[0] += __uint_as_float(v.x << 16);
                a[1] += __uint_as_float(v.x & 0xffff0000u);
                a[2] += __uint_as_float(v.y << 16);
                a[3] += __uint_as_float(v.y & 0xffff0000u);
                a[4] += __uint_as_float(v.z << 16);
                a[5] += __uint_as_float(v.z & 0xffff0000u);
                a[6] += __uint_as_float(v.w << 16);
                a[7] += __uint_as_float(v.w & 0xffff0000u);
            }
        }
    }
}

// ------- k_iter: tout = relu(fbonds@W_i + (sum_j msg[bgraph]) @ W_h) bf16 ----
template <bool UNIFIED>
__global__ __launch_bounds__(256) void k_iter(const float* __restrict__ tree,
                                              const u16* __restrict__ tree_bf,
                                              const u16* __restrict__ tin,
                                              const float* __restrict__ fbonds,
                                              const int* __restrict__ bgraph,
                                              const float* __restrict__ W_h,
                                              const float* __restrict__ W_i,
                                              u16* __restrict__ tout) {
    __shared__ float nei[16][HD];
    __shared__ float sfb[16][40];
    __shared__ int   sidx[16][MAXNB];
    int tid = threadIdx.x;
    int b0  = blockIdx.x * 16;

    if (tid < 128) {
        int t = tid >> 3, j = tid & 7;
        sidx[t][j] = bgraph[(size_t)(b0 + t) * MAXNB + j];
    }
    for (int i = tid; i < 16 * 40; i += 256) {
        int t = i / 40, k = i % 40;
        sfb[t][k] = fbonds[(size_t)(b0 + t) * 40 + k];
    }
    __syncthreads();

    {
        int t = tid >> 4;
        int l = tid & 15;
        float a[8];
        gather_row<UNIFIED>(tree, tree_bf, tin, sidx[t], l, a);
        float4* n4 = (float4*)nei[t];
        n4[2 * l]     = make_float4(a[0], a[1], a[2], a[3]);
        n4[2 * l + 1] = make_float4(a[4], a[5], a[6], a[7]);
    }
    __syncthreads();

    int ct = tid & 31;
    int bt = tid >> 5;
    float acc[2][4] = {{0.f, 0.f, 0.f, 0.f}, {0.f, 0.f, 0.f, 0.f}};
    const float4* W4 = (const float4*)W_h;
    for (int k = 0; k < HD; k += 4) {
        float4 a0 = *(const float4*)&nei[bt][k];
        float4 a1 = *(const float4*)&nei[bt + 8][k];
#pragma unroll
        for (int kk = 0; kk < 4; ++kk) {
            float4 w = W4[(k + kk) * 32 + ct];
            float av0 = ((const float*)&a0)[kk];
            float av1 = ((const float*)&a1)[kk];
            acc[0][0] = fmaf(av0, w.x, acc[0][0]);
            acc[0][1] = fmaf(av0, w.y, acc[0][1]);
            acc[0][2] = fmaf(av0, w.z, acc[0][2]);
            acc[0][3] = fmaf(av0, w.w, acc[0][3]);
            acc[1][0] = fmaf(av1, w.x, acc[1][0]);
            acc[1][1] = fmaf(av1, w.y, acc[1][1]);
            acc[1][2] = fmaf(av1, w.z, acc[1][2]);
            acc[1][3] = fmaf(av1, w.w, acc[1][3]);
        }
    }
    const float4* Wi4 = (const float4*)W_i;
    for (int k = 0; k < 40; ++k) {
        float4 w = Wi4[k * 32 + ct];
        float f0 = sfb[bt][k];
        float f1 = sfb[bt + 8][k];
        acc[0][0] = fmaf(f0, w.x, acc[0][0]);
        acc[0][1] = fmaf(f0, w.y, acc[0][1]);
        acc[0][2] = fmaf(f0, w.z, acc[0][2]);
        acc[0][3] = fmaf(f0, w.w, acc[0][3]);
        acc[1][0] = fmaf(f1, w.x, acc[1][0]);
        acc[1][1] = fmaf(f1, w.y, acc[1][1]);
        acc[1][2] = fmaf(f1, w.z, acc[1][2]);
        acc[1][3] = fmaf(f1, w.w, acc[1][3]);
    }
#pragma unroll
    for (int t2 = 0; t2 < 2; ++t2) {
        size_t b = (size_t)b0 + bt + 8 * t2;
        uint2 r;
        r.x = (u32)f2bf(fmaxf(acc[t2][0], 0.f)) | ((u32)f2bf(fmaxf(acc[t2][1], 0.f)) << 16);
        r.y = (u32)f2bf(fmaxf(acc[t2][2], 0.f)) | ((u32)f2bf(fmaxf(acc[t2][3], 0.f)) << 16);
        ((uint2*)(tout + b * HD))[ct] = r;
    }
}

// ---------------- k_atom: atom_hiddens -> atomic segment sums ----------------
template <bool UNIFIED>
__global__ __launch_bounds__(256) void k_atom(const float* __restrict__ tree,
                                              const u16* __restrict__ tree_bf,
                                              const u16* __restrict__ gfin,
                                              const float* __restrict__ fatoms,
                                              const int* __restrict__ agraph,
                                              const int* __restrict__ mol_id,
                                              const float* __restrict__ W_o,
                                              const float* __restrict__ b_o,
                                              float* __restrict__ sums) {
    __shared__ float nei[16][HD];
    __shared__ float sfat[16][36];
    __shared__ int   sidx[16][MAXNB];
    int tid = threadIdx.x;
    int a0  = blockIdx.x * 16;

    if (tid < 128) {
        int t = tid >> 3, j = tid & 7;
        sidx[t][j] = agraph[(size_t)(a0 + t) * MAXNB + j];
    }
    for (int i = tid; i < 16 * 35; i += 256) {
        int t = i / 35, k = i % 35;
        sfat[t][k] = fatoms[(size_t)(a0 + t) * 35 + k];
    }
    __syncthreads();

    {
        int t = tid >> 4;
        int l = tid & 15;
        float a[8];
        gather_row<UNIFIED>(tree, tree_bf, gfin, sidx[t], l, a);
        float4* n4 = (float4*)nei[t];
        n4[2 * l]     = make_float4(a[0], a[1], a[2], a[3]);
        n4[2 * l + 1] = make_float4(a[4], a[5], a[6], a[7]);
    }
    __syncthreads();

    int ct = tid & 31;
    int bt = tid >> 5;
    float4 bo = ((const float4*)b_o)[ct];
    float acc[2][4] = {{bo.x, bo.y, bo.z, bo.w}, {bo.x, bo.y, bo.z, bo.w}};
    const float4* W4 = (const float4*)(W_o + 35 * HD);
    for (int k = 0; k < HD; k += 4) {
        float4 a0v = *(const float4*)&nei[bt][k];
        float4 a1v = *(const float4*)&nei[bt + 8][k];
#pragma unroll
        for (int kk = 0; kk < 4; ++kk) {
            float4 w = W4[(k + kk) * 32 + ct];
            float av0 = ((const float*)&a0v)[kk];
            float av1 = ((const float*)&a1v)[kk];
            acc[0][0] = fmaf(av0, w.x, acc[0][0]);
            acc[0][1] = fmaf(av0, w.y, acc[0][1]);
            acc[0][2] = fmaf(av0, w.z, acc[0][2]);
            acc[0][3] = fmaf(av0, w.w, acc[0][3]);
            acc[1][0] = fmaf(av1, w.x, acc[1][0]);
            acc[1][1] = fmaf(av1, w.y, acc[1][1]);
            acc[1][2] = fmaf(av1, w.z, acc[1][2]);
            acc[1][3] = fmaf(av1, w.w, acc[1][3]);
        }
    }
    const float4* W4a = (const float4*)W_o;
    for (int k = 0; k < 35; ++k) {
        float4 w = W4a[k * 32 + ct];
        float f0 = sfat[bt][k];
        float f1 = sfat[bt + 8][k];
        acc[0][0] = fmaf(f0, w.x, acc[0][0]);
        acc[0][1] = fmaf(f0, w.y, acc[0][1]);
        acc[0][2] = fmaf(f0, w.z, acc[0][2]);
        acc[0][3] = fmaf(f0, w.w, acc[0][3]);
        acc[1][0] = fmaf(f1, w.x, acc[1][0]);
        acc[1][1] = fmaf(f1, w.y, acc[1][1]);
        acc[1][2] = fmaf(f1, w.z, acc[1][2]);
        acc[1][3] = fmaf(f1, w.w, acc[1][3]);
    }
#pragma unroll
    for (int t2 = 0; t2 < 2; ++t2) {
        int a = a0 + bt + 8 * t2;
        int m = mol_id[a];
        float* dst = sums + (size_t)m * HD + 4 * ct;
        atomicAdd(dst + 0, fmaxf(acc[t2][0], 0.f));
        atomicAdd(dst + 1, fmaxf(acc[t2][1], 0.f));
        atomicAdd(dst + 2, fmaxf(acc[t2][2], 0.f));
        atomicAdd(dst + 3, fmaxf(acc[t2][3], 0.f));
    }
}

// ---------------- k_counts / k_div -------------------------------------------
__global__ __launch_bounds__(256) void k_counts(const int* __restrict__ mol_id,
                                                float* __restrict__ counts) {
    int a = blockIdx.x * 256 + threadIdx.x;
    if (a < AN) atomicAdd(&counts[mol_id[a]], 1.f);
}

__global__ __launch_bounds__(256) void k_div(const float* __restrict__ sums,
                                             const float* __restrict__ counts,
                                             float* __restrict__ out) {
    int i = blockIdx.x * 256 + threadIdx.x;
    if (i < NMOL * HD) out[i] = sums[i] / fmaxf(counts[i >> 7], 1.f);
}

extern "C" void kernel_launch(void* const* d_in, const int* in_sizes, int n_in,
                              void* d_out, int out_size, void* d_ws, size_t ws_size,
                              hipStream_t stream) {
    const float* fatoms = (const float*)d_in[0];
    const float* fbonds = (const float*)d_in[1];
    const float* tree   = (const float*)d_in[2];
    const int*   agraph = (const int*)d_in[3];
    const int*   bgraph = (const int*)d_in[4];
    const int*   mol_id = (const int*)d_in[5];
    const float* W_i    = (const float*)d_in[6];
    const float* W_h    = (const float*)d_in[7];
    const float* W_o    = (const float*)d_in[8];
    const float* b_o    = (const float*)d_in[9];
    float* out = (float*)d_out;

    // layout: t0 | t1 | [tree_bf] | sums | counts
    size_t tbl  = (size_t)BN * HD;                  // u16 elements per table
    size_t base = 2 * tbl;                          // u16 elements for t0+t1
    size_t need_unified = (base + (size_t)MN * HD) * 2 + (size_t)(NMOL * HD + NMOL) * 4;
    bool unified = ws_size >= need_unified;

    u16*   t0      = (u16*)d_ws;
    u16*   t1      = t0 + tbl;
    u16*   tree_bf = unified ? (t1 + tbl) : nullptr;
    float* sums    = (float*)(unified ? (void*)(tree_bf + (size_t)MN * HD) : (void*)(t1 + tbl));
    float* counts  = sums + (size_t)NMOL * HD;

    hipMemsetAsync(sums, 0, (size_t)(NMOL * HD + NMOL) * sizeof(float), stream);

    if (unified)
        k_tree<<<(MN * HD / 4) / 256, 256, 0, stream>>>(tree, tree_bf);

    k_binput<<<BN / 16, 256, 0, stream>>>(fbonds, W_i, t0);

    u16* cur = t0;
    u16* nxt = t1;
    for (int it = 0; it < 4; ++it) {
        if (unified)
            k_iter<true><<<BN / 16, 256, 0, stream>>>(tree, tree_bf, cur, fbonds, bgraph, W_h, W_i, nxt);
        else
            k_iter<false><<<BN / 16, 256, 0, stream>>>(tree, tree_bf, cur, fbonds, bgraph, W_h, W_i, nxt);
        u16* t = cur; cur = nxt; nxt = t;
    }

    k_counts<<<(AN + 255) / 256, 256, 0, stream>>>(mol_id, counts);
    if (unified)
        k_atom<true><<<AN / 16, 256, 0, stream>>>(tree, tree_bf, cur, fatoms, agraph, mol_id, W_o, b_o, sums);
    else
        k_atom<false><<<AN / 16, 256, 0, stream>>>(tree, tree_bf, cur, fatoms, agraph, mol_id, W_o, b_o, sums);
    k_div<<<(NMOL * HD) / 256, 256, 0, stream>>>(sums, counts, out);
}

// Round 4
// 671.324 us; speedup vs baseline: 2.3506x; 2.2887x over previous
//
#include <hip/hip_runtime.h>
#include <hip/hip_bf16.h>

#define AN 100000
#define BN 200000
#define MN 50000
#define HD 128
#define NMOL 4000
#define MAXNB 8
#define BSZ 24576   // u16 elements per swizzled B table (192x128)

typedef unsigned short u16;
typedef unsigned int   u32;
typedef float f32x4 __attribute__((ext_vector_type(4)));
typedef short s16x8 __attribute__((ext_vector_type(8)));

__device__ __forceinline__ u16 f2bf(float x) {
    u32 u = __float_as_uint(x);
    return (u16)((u + 0x7fffu + ((u >> 16) & 1u)) >> 16);
}

// ---------------- k_tree: tree fp32 -> bf16 table ----------------------------
__global__ __launch_bounds__(256) void k_tree(const float* __restrict__ tree,
                                              u16* __restrict__ tree_bf) {
    int i = blockIdx.x * 256 + threadIdx.x;
    const float4 v = ((const float4*)tree)[i];
    uint2 r;
    r.x = (u32)f2bf(v.x) | ((u32)f2bf(v.y) << 16);
    r.y = (u32)f2bf(v.z) | ((u32)f2bf(v.w) << 16);
    ((uint2*)tree_bf)[i] = r;
}

// ------ k_prepB: build MFMA-fragment-order B tables (iter & atom) ------------
// layout: element ((kt*8+nt)*64 + lane)*8 + j  <->  B[k=kt*32+(lane>>4)*8+j][n=nt*16+(lane&15)]
__global__ __launch_bounds__(256) void k_prepB(const float* __restrict__ W_h,
                                               const float* __restrict__ W_i,
                                               const float* __restrict__ W_o,
                                               const float* __restrict__ b_o,
                                               u16* __restrict__ Bit,
                                               u16* __restrict__ Bat) {
    int i = blockIdx.x * 256 + threadIdx.x;
    int which = (i >= BSZ);
    int e = which ? i - BSZ : i;
    int j = e & 7, lane = (e >> 3) & 63, nt = (e >> 9) & 7, kt = e >> 12;
    int k = kt * 32 + (lane >> 4) * 8 + j;
    int n = nt * 16 + (lane & 15);
    if (!which) {
        float v = (k < 128) ? W_h[k * 128 + n] : ((k < 168) ? W_i[(k - 128) * 128 + n] : 0.f);
        Bit[e] = f2bf(v);
    } else {
        float v = (k < 128) ? W_o[(35 + k) * 128 + n]
                : (k < 163) ? W_o[(k - 128) * 128 + n]
                : (k == 163) ? b_o[n] : 0.f;
        Bat[e] = f2bf(v);
    }
}

// ---------------- k_binput: g0 = relu(fbonds @ W_i) as bf16 ------------------
__global__ __launch_bounds__(256) void k_binput(const float* __restrict__ fbonds,
                                                const float* __restrict__ W_i,
                                                u16* __restrict__ g0) {
    __shared__ float sW[40 * HD];
    __shared__ float sfb[16][40];
    int tid = threadIdx.x;
    int b0  = blockIdx.x * 16;
    for (int i = tid; i < 40 * HD; i += 256) sW[i] = W_i[i];
    for (int i = tid; i < 16 * 40; i += 256) {
        int t = i / 40, k = i % 40;
        sfb[t][k] = fbonds[(size_t)(b0 + t) * 40 + k];
    }
    __syncthreads();
    int c  = tid & 127;
    int th = tid >> 7;
#pragma unroll
    for (int q = 0; q < 8; ++q) {
        int t = th + 2 * q;
        float acc = 0.f;
#pragma unroll
        for (int k = 0; k < 40; ++k) acc = fmaf(sfb[t][k], sW[k * HD + c], acc);
        g0[(size_t)(b0 + t) * HD + c] = f2bf(fmaxf(acc, 0.f));
    }
}

// ======================= MFMA path ==========================================
// A-tile [64 x 192] bf16 in LDS, row stride 200 u16 (+8 pad).
// A-frag (16x16x32): lane holds A[m=lane&15][k=(lane>>4)*8+j]
// D-frag: row = (lane>>4)*4+reg, col = lane&15

#define LDA 200

__device__ __forceinline__ void gather_to_sA(u16 (*sA)[LDA], const int (*sidx)[MAXNB],
                                             const u16* __restrict__ tree_bf,
                                             const u16* __restrict__ tin, int tid) {
    int l  = tid & 15;
    int tb = tid >> 4;
#pragma unroll
    for (int p = 0; p < 4; ++p) {
        int t = tb + p * 16;
        uint4 v[MAXNB];
#pragma unroll
        for (int j = 0; j < MAXNB; ++j) {
            int idx = sidx[t][j];
            const u16* base = (idx < MN) ? (tree_bf + (size_t)idx * HD)
                                         : (tin + (size_t)(idx - MN) * HD);
            v[j] = ((const uint4*)base)[l];
        }
        float a[8] = {0.f, 0.f, 0.f, 0.f, 0.f, 0.f, 0.f, 0.f};
#pragma unroll
        for (int j = 0; j < MAXNB; ++j) {
            a[0] += __uint_as_float(v[j].x << 16);
            a[1] += __uint_as_float(v[j].x & 0xffff0000u);
            a[2] += __uint_as_float(v[j].y << 16);
            a[3] += __uint_as_float(v[j].y & 0xffff0000u);
            a[4] += __uint_as_float(v[j].z << 16);
            a[5] += __uint_as_float(v[j].z & 0xffff0000u);
            a[6] += __uint_as_float(v[j].w << 16);
            a[7] += __uint_as_float(v[j].w & 0xffff0000u);
        }
        uint4 r;
        r.x = (u32)f2bf(a[0]) | ((u32)f2bf(a[1]) << 16);
        r.y = (u32)f2bf(a[2]) | ((u32)f2bf(a[3]) << 16);
        r.z = (u32)f2bf(a[4]) | ((u32)f2bf(a[5]) << 16);
        r.w = (u32)f2bf(a[6]) | ((u32)f2bf(a[7]) << 16);
        *(uint4*)&sA[t][l * 8] = r;
    }
}

__global__ __launch_bounds__(256) void k_iter_mfma(const u16* __restrict__ tree_bf,
                                                   const u16* __restrict__ tin,
                                                   const float* __restrict__ fbonds,
                                                   const int* __restrict__ bgraph,
                                                   const u16* __restrict__ Bsw,
                                                   u16* __restrict__ tout) {
    __shared__ __align__(16) u16 sA[64][LDA];
    __shared__ int sidx[64][MAXNB];
    int tid = threadIdx.x;
    int b0  = blockIdx.x * 64;

    for (int i = tid; i < 64 * MAXNB; i += 256)
        sidx[i >> 3][i & 7] = bgraph[(size_t)(b0 + (i >> 3)) * MAXNB + (i & 7)];
    for (int i = tid; i < 64 * 64; i += 256) {            // cols 128..191
        int b = i >> 6, c = i & 63;
        float v = (c < 40) ? fbonds[(size_t)(b0 + b) * 40 + c] : 0.f;
        sA[b][128 + c] = f2bf(v);
    }
    __syncthreads();

    gather_to_sA(sA, sidx, tree_bf, tin, tid);
    __syncthreads();

    int lane = tid & 63;
    int wv   = tid >> 6;
    int am = lane & 15, aq = lane >> 4;
    s16x8 afr[6];
#pragma unroll
    for (int kt = 0; kt < 6; ++kt)
        afr[kt] = *(const s16x8*)&sA[wv * 16 + am][kt * 32 + aq * 8];
    f32x4 acc[8];
#pragma unroll
    for (int nt = 0; nt < 8; ++nt) acc[nt] = (f32x4){0.f, 0.f, 0.f, 0.f};
    const s16x8* B8 = (const s16x8*)Bsw;
#pragma unroll
    for (int kt = 0; kt < 6; ++kt) {
#pragma unroll
        for (int nt = 0; nt < 8; ++nt) {
            s16x8 bfr = B8[(kt * 8 + nt) * 64 + lane];
            acc[nt] = __builtin_amdgcn_mfma_f32_16x16x32_bf16(afr[kt], bfr, acc[nt], 0, 0, 0);
        }
    }
#pragma unroll
    for (int nt = 0; nt < 8; ++nt) {
#pragma unroll
        for (int r = 0; r < 4; ++r) {
            int row = wv * 16 + aq * 4 + r;
            int col = nt * 16 + am;
            tout[(size_t)(b0 + row) * HD + col] = f2bf(fmaxf(acc[nt][r], 0.f));
        }
    }
}

__global__ __launch_bounds__(256) void k_atom_mfma(const u16* __restrict__ tree_bf,
                                                   const u16* __restrict__ gfin,
                                                   const float* __restrict__ fatoms,
                                                   const int* __restrict__ agraph,
                                                   const int* __restrict__ mol_id,
                                                   const u16* __restrict__ Bsw,
                                                   float* __restrict__ sums) {
    __shared__ __align__(16) u16 sA[64][LDA];
    __shared__ float sC[64 * 132];
    __shared__ int sidx[64][MAXNB];
    __shared__ int smol[64];
    int tid = threadIdx.x;
    int a0  = blockIdx.x * 64;

    for (int i = tid; i < 64 * MAXNB; i += 256) {
        int a = a0 + (i >> 3);
        sidx[i >> 3][i & 7] = (a < AN) ? agraph[(size_t)a * MAXNB + (i & 7)] : 0;
    }
    if (tid < 64) smol[tid] = (a0 + tid < AN) ? mol_id[a0 + tid] : -1;
    for (int i = tid; i < 64 * 64; i += 256) {            // cols 128..191
        int b = i >> 6, c = i & 63;
        float v = 0.f;
        if (a0 + b < AN) {
            if (c < 35) v = fatoms[(size_t)(a0 + b) * 35 + c];
            else if (c == 35) v = 1.f;                    // bias column
        }
        sA[b][128 + c] = f2bf(v);
    }
    __syncthreads();

    gather_to_sA(sA, sidx, tree_bf, gfin, tid);
    __syncthreads();

    int lane = tid & 63;
    int wv   = tid >> 6;
    int am = lane & 15, aq = lane >> 4;
    s16x8 afr[6];
#pragma unroll
    for (int kt = 0; kt < 6; ++kt)
        afr[kt] = *(const s16x8*)&sA[wv * 16 + am][kt * 32 + aq * 8];
    f32x4 acc[8];
#pragma unroll
    for (int nt = 0; nt < 8; ++nt) acc[nt] = (f32x4){0.f, 0.f, 0.f, 0.f};
    const s16x8* B8 = (const s16x8*)Bsw;
#pragma unroll
    for (int kt = 0; kt < 6; ++kt) {
#pragma unroll
        for (int nt = 0; nt < 8; ++nt) {
            s16x8 bfr = B8[(kt * 8 + nt) * 64 + lane];
            acc[nt] = __builtin_amdgcn_mfma_f32_16x16x32_bf16(afr[kt], bfr, acc[nt], 0, 0, 0);
        }
    }
#pragma unroll
    for (int nt = 0; nt < 8; ++nt) {
#pragma unroll
        for (int r = 0; r < 4; ++r) {
            int row = wv * 16 + aq * 4 + r;
            int col = nt * 16 + am;
            sC[row * 132 + col] = fmaxf(acc[nt][r], 0.f);
        }
    }
    __syncthreads();

    // sorted-run reduction: 2 halves x 128 cols; few atomics per run
    {
        int c = tid & 127, half = tid >> 7;
        int base = half * 32;
        float run = 0.f;
        int cur = smol[base];
        for (int r = 0; r < 32; ++r) {
            int row = base + r;
            int mv = smol[row];
            if (mv != cur) {
                if (cur >= 0) atomicAdd(&sums[(size_t)cur * HD + c], run);
                run = 0.f; cur = mv;
            }
            run += sC[row * 132 + c];
        }
        if (cur >= 0) atomicAdd(&sums[(size_t)cur * HD + c], run);
    }
}

// ======================= fallback (round-3, known-good) ======================
template <bool UNIFIED>
__device__ __forceinline__ void gather_row(const float* __restrict__ tree,
                                           const u16* __restrict__ tree_bf,
                                           const u16* __restrict__ tin,
                                           const int* sidx_t, int l,
                                           float* __restrict__ a) {
#pragma unroll
    for (int q = 0; q < 8; ++q) a[q] = 0.f;
    if (UNIFIED) {
        uint4 v[MAXNB];
#pragma unroll
        for (int j = 0; j < MAXNB; ++j) {
            int idx = sidx_t[j];
            const u16* base = (idx < MN) ? (tree_bf + (size_t)idx * HD)
                                         : (tin + (size_t)(idx - MN) * HD);
            v[j] = ((const uint4*)base)[l];
        }
#pragma unroll
        for (int j = 0; j < MAXNB; ++j) {
            a[0] += __uint_as_float(v[j].x << 16);
            a[1] += __uint_as_float(v[j].x & 0xffff0000u);
            a[2] += __uint_as_float(v[j].y << 16);
            a[3] += __uint_as_float(v[j].y & 0xffff0000u);
            a[4] += __uint_as_float(v[j].z << 16);
            a[5] += __uint_as_float(v[j].z & 0xffff0000u);
            a[6] += __uint_as_float(v[j].w << 16);
            a[7] += __uint_as_float(v[j].w & 0xffff0000u);
        }
    } else {
#pragma unroll
        for (int j = 0; j < MAXNB; ++j) {
            int idx = sidx_t[j];
            if (idx < MN) {
                const float4* r4 = (const float4*)(tree + (size_t)idx * HD);
                float4 v0 = r4[2 * l], v1 = r4[2 * l + 1];
                a[0] += v0.x; a[1] += v0.y; a[2] += v0.z; a[3] += v0.w;
                a[4] += v1.x; a[5] += v1.y; a[6] += v1.z; a[7] += v1.w;
            } else {
                const uint4* r4 = (const uint4*)(tin + (size_t)(idx - MN) * HD);
                uint4 v = r4[l];
                a[0] += __uint_as_float(v.x << 16);
                a[1] += __uint_as_float(v.x & 0xffff0000u);
                a[2] += __uint_as_float(v.y << 16);
                a[3] += __uint_as_float(v.y & 0xffff0000u);
                a[4] += __uint_as_float(v.z << 16);
                a[5] += __uint_as_float(v.z & 0xffff0000u);
                a[6] += __uint_as_float(v.w << 16);
                a[7] += __uint_as_float(v.w & 0xffff0000u);
            }
        }
    }
}

template <bool UNIFIED>
__global__ __launch_bounds__(256) void k_iter(const float* __restrict__ tree,
                                              const u16* __restrict__ tree_bf,
                                              const u16* __restrict__ tin,
                                              const float* __restrict__ fbonds,
                                              const int* __restrict__ bgraph,
                                              const float* __restrict__ W_h,
                                              const float* __restrict__ W_i,
                                              u16* __restrict__ tout) {
    __shared__ float nei[16][HD];
    __shared__ float sfb[16][40];
    __shared__ int   sidx[16][MAXNB];
    int tid = threadIdx.x;
    int b0  = blockIdx.x * 16;
    if (tid < 128) {
        int t = tid >> 3, j = tid & 7;
        sidx[t][j] = bgraph[(size_t)(b0 + t) * MAXNB + j];
    }
    for (int i = tid; i < 16 * 40; i += 256) {
        int t = i / 40, k = i % 40;
        sfb[t][k] = fbonds[(size_t)(b0 + t) * 40 + k];
    }
    __syncthreads();
    {
        int t = tid >> 4, l = tid & 15;
        float a[8];
        gather_row<UNIFIED>(tree, tree_bf, tin, sidx[t], l, a);
        float4* n4 = (float4*)nei[t];
        n4[2 * l]     = make_float4(a[0], a[1], a[2], a[3]);
        n4[2 * l + 1] = make_float4(a[4], a[5], a[6], a[7]);
    }
    __syncthreads();
    int ct = tid & 31, bt = tid >> 5;
    float acc[2][4] = {{0,0,0,0},{0,0,0,0}};
    const float4* W4 = (const float4*)W_h;
    for (int k = 0; k < HD; k += 4) {
        float4 a0 = *(const float4*)&nei[bt][k];
        float4 a1 = *(const float4*)&nei[bt + 8][k];
#pragma unroll
        for (int kk = 0; kk < 4; ++kk) {
            float4 w = W4[(k + kk) * 32 + ct];
            float av0 = ((const float*)&a0)[kk];
            float av1 = ((const float*)&a1)[kk];
            acc[0][0] = fmaf(av0, w.x, acc[0][0]); acc[0][1] = fmaf(av0, w.y, acc[0][1]);
            acc[0][2] = fmaf(av0, w.z, acc[0][2]); acc[0][3] = fmaf(av0, w.w, acc[0][3]);
            acc[1][0] = fmaf(av1, w.x, acc[1][0]); acc[1][1] = fmaf(av1, w.y, acc[1][1]);
            acc[1][2] = fmaf(av1, w.z, acc[1][2]); acc[1][3] = fmaf(av1, w.w, acc[1][3]);
        }
    }
    const float4* Wi4 = (const float4*)W_i;
    for (int k = 0; k < 40; ++k) {
        float4 w = Wi4[k * 32 + ct];
        float f0 = sfb[bt][k], f1 = sfb[bt + 8][k];
        acc[0][0] = fmaf(f0, w.x, acc[0][0]); acc[0][1] = fmaf(f0, w.y, acc[0][1]);
        acc[0][2] = fmaf(f0, w.z, acc[0][2]); acc[0][3] = fmaf(f0, w.w, acc[0][3]);
        acc[1][0] = fmaf(f1, w.x, acc[1][0]); acc[1][1] = fmaf(f1, w.y, acc[1][1]);
        acc[1][2] = fmaf(f1, w.z, acc[1][2]); acc[1][3] = fmaf(f1, w.w, acc[1][3]);
    }
#pragma unroll
    for (int t2 = 0; t2 < 2; ++t2) {
        size_t b = (size_t)b0 + bt + 8 * t2;
        uint2 r;
        r.x = (u32)f2bf(fmaxf(acc[t2][0], 0.f)) | ((u32)f2bf(fmaxf(acc[t2][1], 0.f)) << 16);
        r.y = (u32)f2bf(fmaxf(acc[t2][2], 0.f)) | ((u32)f2bf(fmaxf(acc[t2][3], 0.f)) << 16);
        ((uint2*)(tout + b * HD))[ct] = r;
    }
}

template <bool UNIFIED>
__global__ __launch_bounds__(256) void k_atom(const float* __restrict__ tree,
                                              const u16* __restrict__ tree_bf,
                                              const u16* __restrict__ gfin,
                                              const float* __restrict__ fatoms,
                                              const int* __restrict__ agraph,
                                              const int* __restrict__ mol_id,
                                              const float* __restrict__ W_o,
                                              const float* __restrict__ b_o,
                                              float* __restrict__ sums) {
    __shared__ float nei[16][HD];
    __shared__ float sfat[16][36];
    __shared__ int   sidx[16][MAXNB];
    int tid = threadIdx.x;
    int a0  = blockIdx.x * 16;
    if (tid < 128) {
        int t = tid >> 3, j = tid & 7;
        sidx[t][j] = agraph[(size_t)(a0 + t) * MAXNB + j];
    }
    for (int i = tid; i < 16 * 35; i += 256) {
        int t = i / 35, k = i % 35;
        sfat[t][k] = fatoms[(size_t)(a0 + t) * 35 + k];
    }
    __syncthreads();
    {
        int t = tid >> 4, l = tid & 15;
        float a[8];
        gather_row<UNIFIED>(tree, tree_bf, gfin, sidx[t], l, a);
        float4* n4 = (float4*)nei[t];
        n4[2 * l]     = make_float4(a[0], a[1], a[2], a[3]);
        n4[2 * l + 1] = make_float4(a[4], a[5], a[6], a[7]);
    }
    __syncthreads();
    int ct = tid & 31, bt = tid >> 5;
    float4 bo = ((const float4*)b_o)[ct];
    float acc[2][4] = {{bo.x, bo.y, bo.z, bo.w}, {bo.x, bo.y, bo.z, bo.w}};
    const float4* W4 = (const float4*)(W_o + 35 * HD);
    for (int k = 0; k < HD; k += 4) {
        float4 a0v = *(const float4*)&nei[bt][k];
        float4 a1v = *(const float4*)&nei[bt + 8][k];
#pragma unroll
        for (int kk = 0; kk < 4; ++kk) {
            float4 w = W4[(k + kk) * 32 + ct];
            float av0 = ((const float*)&a0v)[kk];
            float av1 = ((const float*)&a1v)[kk];
            acc[0][0] = fmaf(av0, w.x, acc[0][0]); acc[0][1] = fmaf(av0, w.y, acc[0][1]);
            acc[0][2] = fmaf(av0, w.z, acc[0][2]); acc[0][3] = fmaf(av0, w.w, acc[0][3]);
            acc[1][0] = fmaf(av1, w.x, acc[1][0]); acc[1][1] = fmaf(av1, w.y, acc[1][1]);
            acc[1][2] = fmaf(av1, w.z, acc[1][2]); acc[1][3] = fmaf(av1, w.w, acc[1][3]);
        }
    }
    const float4* W4a = (const float4*)W_o;
    for (int k = 0; k < 35; ++k) {
        float4 w = W4a[k * 32 + ct];
        float f0 = sfat[bt][k], f1 = sfat[bt + 8][k];
        acc[0][0] = fmaf(f0, w.x, acc[0][0]); acc[0][1] = fmaf(f0, w.y, acc[0][1]);
        acc[0][2] = fmaf(f0, w.z, acc[0][2]); acc[0][3] = fmaf(f0, w.w, acc[0][3]);
        acc[1][0] = fmaf(f1, w.x, acc[1][0]); acc[1][1] = fmaf(f1, w.y, acc[1][1]);
        acc[1][2] = fmaf(f1, w.z, acc[1][2]); acc[1][3] = fmaf(f1, w.w, acc[1][3]);
    }
#pragma unroll
    for (int t2 = 0; t2 < 2; ++t2) {
        int a = a0 + bt + 8 * t2;
        int m = mol_id[a];
        float* dst = sums + (size_t)m * HD + 4 * ct;
        atomicAdd(dst + 0, fmaxf(acc[t2][0], 0.f));
        atomicAdd(dst + 1, fmaxf(acc[t2][1], 0.f));
        atomicAdd(dst + 2, fmaxf(acc[t2][2], 0.f));
        atomicAdd(dst + 3, fmaxf(acc[t2][3], 0.f));
    }
}

// ---------------- k_counts / k_div -------------------------------------------
__global__ __launch_bounds__(256) void k_counts(const int* __restrict__ mol_id,
                                                float* __restrict__ counts) {
    int a = blockIdx.x * 256 + threadIdx.x;
    if (a < AN) atomicAdd(&counts[mol_id[a]], 1.f);
}

__global__ __launch_bounds__(256) void k_div(const float* __restrict__ sums,
                                             const float* __restrict__ counts,
                                             float* __restrict__ out) {
    int i = blockIdx.x * 256 + threadIdx.x;
    if (i < NMOL * HD) out[i] = sums[i] / fmaxf(counts[i >> 7], 1.f);
}

extern "C" void kernel_launch(void* const* d_in, const int* in_sizes, int n_in,
                              void* d_out, int out_size, void* d_ws, size_t ws_size,
                              hipStream_t stream) {
    const float* fatoms = (const float*)d_in[0];
    const float* fbonds = (const float*)d_in[1];
    const float* tree   = (const float*)d_in[2];
    const int*   agraph = (const int*)d_in[3];
    const int*   bgraph = (const int*)d_in[4];
    const int*   mol_id = (const int*)d_in[5];
    const float* W_i    = (const float*)d_in[6];
    const float* W_h    = (const float*)d_in[7];
    const float* W_o    = (const float*)d_in[8];
    const float* b_o    = (const float*)d_in[9];
    float* out = (float*)d_out;

    size_t tbl   = (size_t)BN * HD;     // u16 per message table
    size_t treeN = (size_t)MN * HD;     // u16 for tree_bf
    size_t redN  = (size_t)(NMOL * HD + NMOL);

    u16* t0 = (u16*)d_ws;
    u16* t1 = t0 + tbl;

    size_t need_mfma = (2 * tbl + treeN + 2 * BSZ) * 2 + redN * 4;
    size_t need_uni  = (2 * tbl + treeN) * 2 + redN * 4;

    if (ws_size >= need_mfma) {
        u16* tree_bf = t1 + tbl;
        u16* Bit     = tree_bf + treeN;
        u16* Bat     = Bit + BSZ;
        float* sums   = (float*)(Bat + BSZ);
        float* counts = sums + (size_t)NMOL * HD;

        hipMemsetAsync(sums, 0, redN * sizeof(float), stream);
        k_tree<<<(MN * HD / 4) / 256, 256, 0, stream>>>(tree, tree_bf);
        k_prepB<<<(2 * BSZ) / 256, 256, 0, stream>>>(W_h, W_i, W_o, b_o, Bit, Bat);
        k_binput<<<BN / 16, 256, 0, stream>>>(fbonds, W_i, t0);

        u16* cur = t0;
        u16* nxt = t1;
        for (int it = 0; it < 4; ++it) {
            k_iter_mfma<<<BN / 64, 256, 0, stream>>>(tree_bf, cur, fbonds, bgraph, Bit, nxt);
            u16* t = cur; cur = nxt; nxt = t;
        }
        k_counts<<<(AN + 255) / 256, 256, 0, stream>>>(mol_id, counts);
        k_atom_mfma<<<(AN + 63) / 64, 256, 0, stream>>>(tree_bf, cur, fatoms, agraph,
                                                        mol_id, Bat, sums);
        k_div<<<(NMOL * HD) / 256, 256, 0, stream>>>(sums, counts, out);
    } else {
        bool unified = ws_size >= need_uni;
        u16* tree_bf = unified ? (t1 + tbl) : nullptr;
        float* sums   = (float*)(unified ? (void*)(tree_bf + treeN) : (void*)(t1 + tbl));
        float* counts = sums + (size_t)NMOL * HD;

        hipMemsetAsync(sums, 0, redN * sizeof(float), stream);
        if (unified)
            k_tree<<<(MN * HD / 4) / 256, 256, 0, stream>>>(tree, tree_bf);
        k_binput<<<BN / 16, 256, 0, stream>>>(fbonds, W_i, t0);

        u16* cur = t0;
        u16* nxt = t1;
        for (int it = 0; it < 4; ++it) {
            if (unified)
                k_iter<true><<<BN / 16, 256, 0, stream>>>(tree, tree_bf, cur, fbonds, bgraph, W_h, W_i, nxt);
            else
                k_iter<false><<<BN / 16, 256, 0, stream>>>(tree, tree_bf, cur, fbonds, bgraph, W_h, W_i, nxt);
            u16* t = cur; cur = nxt; nxt = t;
        }
        k_counts<<<(AN + 255) / 256, 256, 0, stream>>>(mol_id, counts);
        if (unified)
            k_atom<true><<<AN / 16, 256, 0, stream>>>(tree, tree_bf, cur, fatoms, agraph, mol_id, W_o, b_o, sums);
        else
            k_atom<false><<<AN / 16, 256, 0, stream>>>(tree, tree_bf, cur, fatoms, agraph, mol_id, W_o, b_o, sums);
        k_div<<<(NMOL * HD) / 256, 256, 0, stream>>>(sums, counts, out);
    }
}

// Round 5
// 555.093 us; speedup vs baseline: 2.8428x; 1.2094x over previous
//
#include <hip/hip_runtime.h>
#include <hip/hip_bf16.h>

#define AN 100000
#define BN 200000
#define MN 50000
#define HD 128
#define NMOL 4000
#define MAXNB 8
#define BSZ 24576   // u16 elements per swizzled B table (192x128)

typedef unsigned short u16;
typedef unsigned int   u32;
typedef float f32x4 __attribute__((ext_vector_type(4)));
typedef short s16x8 __attribute__((ext_vector_type(8)));

__device__ __forceinline__ u16 f2bf(float x) {
    u32 u = __float_as_uint(x);
    return (u16)((u + 0x7fffu + ((u >> 16) & 1u)) >> 16);
}

// ---------------- k_tree: tree fp32 -> bf16 table ----------------------------
__global__ __launch_bounds__(256) void k_tree(const float* __restrict__ tree,
                                              u16* __restrict__ tree_bf) {
    int i = blockIdx.x * 256 + threadIdx.x;
    const float4 v = ((const float4*)tree)[i];
    uint2 r;
    r.x = (u32)f2bf(v.x) | ((u32)f2bf(v.y) << 16);
    r.y = (u32)f2bf(v.z) | ((u32)f2bf(v.w) << 16);
    ((uint2*)tree_bf)[i] = r;
}

// ------ k_prepB: build MFMA-fragment-order B tables (iter & atom) ------------
// layout: element ((kt*8+nt)*64 + lane)*8 + j  <->  B[k=kt*32+(lane>>4)*8+j][n=nt*16+(lane&15)]
__global__ __launch_bounds__(256) void k_prepB(const float* __restrict__ W_h,
                                               const float* __restrict__ W_i,
                                               const float* __restrict__ W_o,
                                               const float* __restrict__ b_o,
                                               u16* __restrict__ Bit,
                                               u16* __restrict__ Bat) {
    int i = blockIdx.x * 256 + threadIdx.x;
    int which = (i >= BSZ);
    int e = which ? i - BSZ : i;
    int j = e & 7, lane = (e >> 3) & 63, nt = (e >> 9) & 7, kt = e >> 12;
    int k = kt * 32 + (lane >> 4) * 8 + j;
    int n = nt * 16 + (lane & 15);
    if (!which) {
        float v = (k < 128) ? W_h[k * 128 + n] : ((k < 168) ? W_i[(k - 128) * 128 + n] : 0.f);
        Bit[e] = f2bf(v);
    } else {
        float v = (k < 128) ? W_o[(35 + k) * 128 + n]
                : (k < 163) ? W_o[(k - 128) * 128 + n]
                : (k == 163) ? b_o[n] : 0.f;
        Bat[e] = f2bf(v);
    }
}

// -------- k_binput_mfma: g0 = relu(fbonds @ W_i) via MFMA (uses Bit kt=4,5) --
__global__ __launch_bounds__(256) void k_binput_mfma(const float* __restrict__ fbonds,
                                                     const u16* __restrict__ Bsw,
                                                     u16* __restrict__ g0) {
    __shared__ __align__(16) u16 sA[64][72];
    int tid = threadIdx.x;
    int b0  = blockIdx.x * 64;
    for (int i = tid; i < 64 * 64; i += 256) {
        int b = i >> 6, c = i & 63;
        float v = (c < 40) ? fbonds[(size_t)(b0 + b) * 40 + c] : 0.f;
        sA[b][c] = f2bf(v);
    }
    __syncthreads();
    int lane = tid & 63, wv = tid >> 6;
    int am = lane & 15, aq = lane >> 4;
    s16x8 afr[2];
#pragma unroll
    for (int kt = 0; kt < 2; ++kt)
        afr[kt] = *(const s16x8*)&sA[wv * 16 + am][kt * 32 + aq * 8];
    f32x4 acc[8];
#pragma unroll
    for (int nt = 0; nt < 8; ++nt) acc[nt] = (f32x4){0.f, 0.f, 0.f, 0.f};
    const s16x8* B8 = (const s16x8*)Bsw;
#pragma unroll
    for (int kt = 0; kt < 2; ++kt)
#pragma unroll
        for (int nt = 0; nt < 8; ++nt) {
            s16x8 bfr = B8[((4 + kt) * 8 + nt) * 64 + lane];
            acc[nt] = __builtin_amdgcn_mfma_f32_16x16x32_bf16(afr[kt], bfr, acc[nt], 0, 0, 0);
        }
#pragma unroll
    for (int nt = 0; nt < 8; ++nt)
#pragma unroll
        for (int r = 0; r < 4; ++r) {
            int row = wv * 16 + aq * 4 + r;
            int col = nt * 16 + am;
            g0[(size_t)(b0 + row) * HD + col] = f2bf(fmaxf(acc[nt][r], 0.f));
        }
}

// ======================= MFMA main kernels ===================================
// A-tile [64 x 192] bf16 in LDS, row stride 200 u16 (+8 pad).
// A-frag (16x16x32): lane holds A[m=lane&15][k=(lane>>4)*8+j]
// D-frag: row = (lane>>4)*4+reg, col = lane&15

#define LDA 200

__device__ __forceinline__ void gather_to_sA(u16 (*sA)[LDA], const int (*sidx)[MAXNB],
                                             const u16* __restrict__ tree_bf,
                                             const u16* __restrict__ tin, int tid) {
    int l  = tid & 15;
    int tb = tid >> 4;
#pragma unroll
    for (int p = 0; p < 4; ++p) {
        int t = tb + p * 16;
        uint4 v[MAXNB];
#pragma unroll
        for (int j = 0; j < MAXNB; ++j) {
            int idx = sidx[t][j];
            const u16* base = (idx < MN) ? (tree_bf + (size_t)idx * HD)
                                         : (tin + (size_t)(idx - MN) * HD);
            v[j] = ((const uint4*)base)[l];
        }
        float a[8] = {0.f, 0.f, 0.f, 0.f, 0.f, 0.f, 0.f, 0.f};
#pragma unroll
        for (int j = 0; j < MAXNB; ++j) {
            a[0] += __uint_as_float(v[j].x << 16);
            a[1] += __uint_as_float(v[j].x & 0xffff0000u);
            a[2] += __uint_as_float(v[j].y << 16);
            a[3] += __uint_as_float(v[j].y & 0xffff0000u);
            a[4] += __uint_as_float(v[j].z << 16);
            a[5] += __uint_as_float(v[j].z & 0xffff0000u);
            a[6] += __uint_as_float(v[j].w << 16);
            a[7] += __uint_as_float(v[j].w & 0xffff0000u);
        }
        uint4 r;
        r.x = (u32)f2bf(a[0]) | ((u32)f2bf(a[1]) << 16);
        r.y = (u32)f2bf(a[2]) | ((u32)f2bf(a[3]) << 16);
        r.z = (u32)f2bf(a[4]) | ((u32)f2bf(a[5]) << 16);
        r.w = (u32)f2bf(a[6]) | ((u32)f2bf(a[7]) << 16);
        *(uint4*)&sA[t][l * 8] = r;
    }
}

__global__ __launch_bounds__(256) void k_iter_mfma(const u16* __restrict__ tree_bf,
                                                   const u16* __restrict__ tin,
                                                   const float* __restrict__ fbonds,
                                                   const int* __restrict__ bgraph,
                                                   const u16* __restrict__ Bsw,
                                                   u16* __restrict__ tout) {
    __shared__ __align__(16) u16 sA[64][LDA];
    __shared__ int sidx[64][MAXNB];
    int tid = threadIdx.x;
    int b0  = blockIdx.x * 64;

    for (int i = tid; i < 64 * MAXNB; i += 256)
        sidx[i >> 3][i & 7] = bgraph[(size_t)(b0 + (i >> 3)) * MAXNB + (i & 7)];
    for (int i = tid; i < 64 * 64; i += 256) {            // cols 128..191
        int b = i >> 6, c = i & 63;
        float v = (c < 40) ? fbonds[(size_t)(b0 + b) * 40 + c] : 0.f;
        sA[b][128 + c] = f2bf(v);
    }
    __syncthreads();

    gather_to_sA(sA, sidx, tree_bf, tin, tid);
    __syncthreads();

    int lane = tid & 63;
    int wv   = tid >> 6;
    int am = lane & 15, aq = lane >> 4;
    s16x8 afr[6];
#pragma unroll
    for (int kt = 0; kt < 6; ++kt)
        afr[kt] = *(const s16x8*)&sA[wv * 16 + am][kt * 32 + aq * 8];
    f32x4 acc[8];
#pragma unroll
    for (int nt = 0; nt < 8; ++nt) acc[nt] = (f32x4){0.f, 0.f, 0.f, 0.f};
    const s16x8* B8 = (const s16x8*)Bsw;
#pragma unroll
    for (int kt = 0; kt < 6; ++kt) {
#pragma unroll
        for (int nt = 0; nt < 8; ++nt) {
            s16x8 bfr = B8[(kt * 8 + nt) * 64 + lane];
            acc[nt] = __builtin_amdgcn_mfma_f32_16x16x32_bf16(afr[kt], bfr, acc[nt], 0, 0, 0);
        }
    }
#pragma unroll
    for (int nt = 0; nt < 8; ++nt) {
#pragma unroll
        for (int r = 0; r < 4; ++r) {
            int row = wv * 16 + aq * 4 + r;
            int col = nt * 16 + am;
            tout[(size_t)(b0 + row) * HD + col] = f2bf(fmaxf(acc[nt][r], 0.f));
        }
    }
}

__global__ __launch_bounds__(256) void k_atom_mfma(const u16* __restrict__ tree_bf,
                                                   const u16* __restrict__ gfin,
                                                   const float* __restrict__ fatoms,
                                                   const int* __restrict__ agraph,
                                                   const int* __restrict__ mol_id,
                                                   const u16* __restrict__ Bsw,
                                                   float* __restrict__ sums) {
    // sA (25.6 KB) and sC (33.8 KB) live in disjoint phases -> alias them
    __shared__ __align__(16) char smem[64 * 132 * sizeof(float)];
    u16   (*sA)[LDA] = (u16 (*)[LDA])smem;
    float* sC        = (float*)smem;
    __shared__ int sidx[64][MAXNB];
    __shared__ int smol[64];
    int tid = threadIdx.x;
    int a0  = blockIdx.x * 64;

    for (int i = tid; i < 64 * MAXNB; i += 256) {
        int a = a0 + (i >> 3);
        sidx[i >> 3][i & 7] = (a < AN) ? agraph[(size_t)a * MAXNB + (i & 7)] : 0;
    }
    if (tid < 64) smol[tid] = (a0 + tid < AN) ? mol_id[a0 + tid] : -1;
    for (int i = tid; i < 64 * 64; i += 256) {            // cols 128..191
        int b = i >> 6, c = i & 63;
        float v = 0.f;
        if (a0 + b < AN) {
            if (c < 35) v = fatoms[(size_t)(a0 + b) * 35 + c];
            else if (c == 35) v = 1.f;                    // bias column
        }
        sA[b][128 + c] = f2bf(v);
    }
    __syncthreads();

    gather_to_sA(sA, sidx, tree_bf, gfin, tid);
    __syncthreads();

    int lane = tid & 63;
    int wv   = tid >> 6;
    int am = lane & 15, aq = lane >> 4;
    s16x8 afr[6];
#pragma unroll
    for (int kt = 0; kt < 6; ++kt)
        afr[kt] = *(const s16x8*)&sA[wv * 16 + am][kt * 32 + aq * 8];
    __syncthreads();   // all waves done reading sA before sC overwrites it

    f32x4 acc[8];
#pragma unroll
    for (int nt = 0; nt < 8; ++nt) acc[nt] = (f32x4){0.f, 0.f, 0.f, 0.f};
    const s16x8* B8 = (const s16x8*)Bsw;
#pragma unroll
    for (int kt = 0; kt < 6; ++kt) {
#pragma unroll
        for (int nt = 0; nt < 8; ++nt) {
            s16x8 bfr = B8[(kt * 8 + nt) * 64 + lane];
            acc[nt] = __builtin_amdgcn_mfma_f32_16x16x32_bf16(afr[kt], bfr, acc[nt], 0, 0, 0);
        }
    }
#pragma unroll
    for (int nt = 0; nt < 8; ++nt) {
#pragma unroll
        for (int r = 0; r < 4; ++r) {
            int row = wv * 16 + aq * 4 + r;
            int col = nt * 16 + am;
            sC[row * 132 + col] = fmaxf(acc[nt][r], 0.f);
        }
    }
    __syncthreads();

    // sorted-run reduction: 2 halves x 128 cols; few atomics per run
    {
        int c = tid & 127, half = tid >> 7;
        int base = half * 32;
        float run = 0.f;
        int cur = smol[base];
        for (int r = 0; r < 32; ++r) {
            int row = base + r;
            int mv = smol[row];
            if (mv != cur) {
                if (cur >= 0) atomicAdd(&sums[(size_t)cur * HD + c], run);
                run = 0.f; cur = mv;
            }
            run += sC[row * 132 + c];
        }
        if (cur >= 0) atomicAdd(&sums[(size_t)cur * HD + c], run);
    }
}

// ======================= fallback (round-3, known-good) ======================
template <bool UNIFIED>
__device__ __forceinline__ void gather_row(const float* __restrict__ tree,
                                           const u16* __restrict__ tree_bf,
                                           const u16* __restrict__ tin,
                                           const int* sidx_t, int l,
                                           float* __restrict__ a) {
#pragma unroll
    for (int q = 0; q < 8; ++q) a[q] = 0.f;
    if (UNIFIED) {
        uint4 v[MAXNB];
#pragma unroll
        for (int j = 0; j < MAXNB; ++j) {
            int idx = sidx_t[j];
            const u16* base = (idx < MN) ? (tree_bf + (size_t)idx * HD)
                                         : (tin + (size_t)(idx - MN) * HD);
            v[j] = ((const uint4*)base)[l];
        }
#pragma unroll
        for (int j = 0; j < MAXNB; ++j) {
            a[0] += __uint_as_float(v[j].x << 16);
            a[1] += __uint_as_float(v[j].x & 0xffff0000u);
            a[2] += __uint_as_float(v[j].y << 16);
            a[3] += __uint_as_float(v[j].y & 0xffff0000u);
            a[4] += __uint_as_float(v[j].z << 16);
            a[5] += __uint_as_float(v[j].z & 0xffff0000u);
            a[6] += __uint_as_float(v[j].w << 16);
            a[7] += __uint_as_float(v[j].w & 0xffff0000u);
        }
    } else {
#pragma unroll
        for (int j = 0; j < MAXNB; ++j) {
            int idx = sidx_t[j];
            if (idx < MN) {
                const float4* r4 = (const float4*)(tree + (size_t)idx * HD);
                float4 v0 = r4[2 * l], v1 = r4[2 * l + 1];
                a[0] += v0.x; a[1] += v0.y; a[2] += v0.z; a[3] += v0.w;
                a[4] += v1.x; a[5] += v1.y; a[6] += v1.z; a[7] += v1.w;
            } else {
                const uint4* r4 = (const uint4*)(tin + (size_t)(idx - MN) * HD);
                uint4 v = r4[l];
                a[0] += __uint_as_float(v.x << 16);
                a[1] += __uint_as_float(v.x & 0xffff0000u);
                a[2] += __uint_as_float(v.y << 16);
                a[3] += __uint_as_float(v.y & 0xffff0000u);
                a[4] += __uint_as_float(v.z << 16);
                a[5] += __uint_as_float(v.z & 0xffff0000u);
                a[6] += __uint_as_float(v.w << 16);
                a[7] += __uint_as_float(v.w & 0xffff0000u);
            }
        }
    }
}

__global__ __launch_bounds__(256) void k_binput(const float* __restrict__ fbonds,
                                                const float* __restrict__ W_i,
                                                u16* __restrict__ g0) {
    __shared__ float sW[40 * HD];
    __shared__ float sfb[16][40];
    int tid = threadIdx.x;
    int b0  = blockIdx.x * 16;
    for (int i = tid; i < 40 * HD; i += 256) sW[i] = W_i[i];
    for (int i = tid; i < 16 * 40; i += 256) {
        int t = i / 40, k = i % 40;
        sfb[t][k] = fbonds[(size_t)(b0 + t) * 40 + k];
    }
    __syncthreads();
    int c  = tid & 127;
    int th = tid >> 7;
#pragma unroll
    for (int q = 0; q < 8; ++q) {
        int t = th + 2 * q;
        float acc = 0.f;
#pragma unroll
        for (int k = 0; k < 40; ++k) acc = fmaf(sfb[t][k], sW[k * HD + c], acc);
        g0[(size_t)(b0 + t) * HD + c] = f2bf(fmaxf(acc, 0.f));
    }
}

template <bool UNIFIED>
__global__ __launch_bounds__(256) void k_iter(const float* __restrict__ tree,
                                              const u16* __restrict__ tree_bf,
                                              const u16* __restrict__ tin,
                                              const float* __restrict__ fbonds,
                                              const int* __restrict__ bgraph,
                                              const float* __restrict__ W_h,
                                              const float* __restrict__ W_i,
                                              u16* __restrict__ tout) {
    __shared__ float nei[16][HD];
    __shared__ float sfb[16][40];
    __shared__ int   sidx[16][MAXNB];
    int tid = threadIdx.x;
    int b0  = blockIdx.x * 16;
    if (tid < 128) {
        int t = tid >> 3, j = tid & 7;
        sidx[t][j] = bgraph[(size_t)(b0 + t) * MAXNB + j];
    }
    for (int i = tid; i < 16 * 40; i += 256) {
        int t = i / 40, k = i % 40;
        sfb[t][k] = fbonds[(size_t)(b0 + t) * 40 + k];
    }
    __syncthreads();
    {
        int t = tid >> 4, l = tid & 15;
        float a[8];
        gather_row<UNIFIED>(tree, tree_bf, tin, sidx[t], l, a);
        float4* n4 = (float4*)nei[t];
        n4[2 * l]     = make_float4(a[0], a[1], a[2], a[3]);
        n4[2 * l + 1] = make_float4(a[4], a[5], a[6], a[7]);
    }
    __syncthreads();
    int ct = tid & 31, bt = tid >> 5;
    float acc[2][4] = {{0,0,0,0},{0,0,0,0}};
    const float4* W4 = (const float4*)W_h;
    for (int k = 0; k < HD; k += 4) {
        float4 a0 = *(const float4*)&nei[bt][k];
        float4 a1 = *(const float4*)&nei[bt + 8][k];
#pragma unroll
        for (int kk = 0; kk < 4; ++kk) {
            float4 w = W4[(k + kk) * 32 + ct];
            float av0 = ((const float*)&a0)[kk];
            float av1 = ((const float*)&a1)[kk];
            acc[0][0] = fmaf(av0, w.x, acc[0][0]); acc[0][1] = fmaf(av0, w.y, acc[0][1]);
            acc[0][2] = fmaf(av0, w.z, acc[0][2]); acc[0][3] = fmaf(av0, w.w, acc[0][3]);
            acc[1][0] = fmaf(av1, w.x, acc[1][0]); acc[1][1] = fmaf(av1, w.y, acc[1][1]);
            acc[1][2] = fmaf(av1, w.z, acc[1][2]); acc[1][3] = fmaf(av1, w.w, acc[1][3]);
        }
    }
    const float4* Wi4 = (const float4*)W_i;
    for (int k = 0; k < 40; ++k) {
        float4 w = Wi4[k * 32 + ct];
        float f0 = sfb[bt][k], f1 = sfb[bt + 8][k];
        acc[0][0] = fmaf(f0, w.x, acc[0][0]); acc[0][1] = fmaf(f0, w.y, acc[0][1]);
        acc[0][2] = fmaf(f0, w.z, acc[0][2]); acc[0][3] = fmaf(f0, w.w, acc[0][3]);
        acc[1][0] = fmaf(f1, w.x, acc[1][0]); acc[1][1] = fmaf(f1, w.y, acc[1][1]);
        acc[1][2] = fmaf(f1, w.z, acc[1][2]); acc[1][3] = fmaf(f1, w.w, acc[1][3]);
    }
#pragma unroll
    for (int t2 = 0; t2 < 2; ++t2) {
        size_t b = (size_t)b0 + bt + 8 * t2;
        uint2 r;
        r.x = (u32)f2bf(fmaxf(acc[t2][0], 0.f)) | ((u32)f2bf(fmaxf(acc[t2][1], 0.f)) << 16);
        r.y = (u32)f2bf(fmaxf(acc[t2][2], 0.f)) | ((u32)f2bf(fmaxf(acc[t2][3], 0.f)) << 16);
        ((uint2*)(tout + b * HD))[ct] = r;
    }
}

template <bool UNIFIED>
__global__ __launch_bounds__(256) void k_atom(const float* __restrict__ tree,
                                              const u16* __restrict__ tree_bf,
                                              const u16* __restrict__ gfin,
                                              const float* __restrict__ fatoms,
                                              const int* __restrict__ agraph,
                                              const int* __restrict__ mol_id,
                                              const float* __restrict__ W_o,
                                              const float* __restrict__ b_o,
                                              float* __restrict__ sums) {
    __shared__ float nei[16][HD];
    __shared__ float sfat[16][36];
    __shared__ int   sidx[16][MAXNB];
    int tid = threadIdx.x;
    int a0  = blockIdx.x * 16;
    if (tid < 128) {
        int t = tid >> 3, j = tid & 7;
        sidx[t][j] = agraph[(size_t)(a0 + t) * MAXNB + j];
    }
    for (int i = tid; i < 16 * 35; i += 256) {
        int t = i / 35, k = i % 35;
        sfat[t][k] = fatoms[(size_t)(a0 + t) * 35 + k];
    }
    __syncthreads();
    {
        int t = tid >> 4, l = tid & 15;
        float a[8];
        gather_row<UNIFIED>(tree, tree_bf, gfin, sidx[t], l, a);
        float4* n4 = (float4*)nei[t];
        n4[2 * l]     = make_float4(a[0], a[1], a[2], a[3]);
        n4[2 * l + 1] = make_float4(a[4], a[5], a[6], a[7]);
    }
    __syncthreads();
    int ct = tid & 31, bt = tid >> 5;
    float4 bo = ((const float4*)b_o)[ct];
    float acc[2][4] = {{bo.x, bo.y, bo.z, bo.w}, {bo.x, bo.y, bo.z, bo.w}};
    const float4* W4 = (const float4*)(W_o + 35 * HD);
    for (int k = 0; k < HD; k += 4) {
        float4 a0v = *(const float4*)&nei[bt][k];
        float4 a1v = *(const float4*)&nei[bt + 8][k];
#pragma unroll
        for (int kk = 0; kk < 4; ++kk) {
            float4 w = W4[(k + kk) * 32 + ct];
            float av0 = ((const float*)&a0v)[kk];
            float av1 = ((const float*)&a1v)[kk];
            acc[0][0] = fmaf(av0, w.x, acc[0][0]); acc[0][1] = fmaf(av0, w.y, acc[0][1]);
            acc[0][2] = fmaf(av0, w.z, acc[0][2]); acc[0][3] = fmaf(av0, w.w, acc[0][3]);
            acc[1][0] = fmaf(av1, w.x, acc[1][0]); acc[1][1] = fmaf(av1, w.y, acc[1][1]);
            acc[1][2] = fmaf(av1, w.z, acc[1][2]); acc[1][3] = fmaf(av1, w.w, acc[1][3]);
        }
    }
    const float4* W4a = (const float4*)W_o;
    for (int k = 0; k < 35; ++k) {
        float4 w = W4a[k * 32 + ct];
        float f0 = sfat[bt][k], f1 = sfat[bt + 8][k];
        acc[0][0] = fmaf(f0, w.x, acc[0][0]); acc[0][1] = fmaf(f0, w.y, acc[0][1]);
        acc[0][2] = fmaf(f0, w.z, acc[0][2]); acc[0][3] = fmaf(f0, w.w, acc[0][3]);
        acc[1][0] = fmaf(f1, w.x, acc[1][0]); acc[1][1] = fmaf(f1, w.y, acc[1][1]);
        acc[1][2] = fmaf(f1, w.z, acc[1][2]); acc[1][3] = fmaf(f1, w.w, acc[1][3]);
    }
#pragma unroll
    for (int t2 = 0; t2 < 2; ++t2) {
        int a = a0 + bt + 8 * t2;
        int m = mol_id[a];
        float* dst = sums + (size_t)m * HD + 4 * ct;
        atomicAdd(dst + 0, fmaxf(acc[t2][0], 0.f));
        atomicAdd(dst + 1, fmaxf(acc[t2][1], 0.f));
        atomicAdd(dst + 2, fmaxf(acc[t2][2], 0.f));
        atomicAdd(dst + 3, fmaxf(acc[t2][3], 0.f));
    }
}

// ---------------- k_counts / k_div -------------------------------------------
__global__ __launch_bounds__(256) void k_counts(const int* __restrict__ mol_id,
                                                float* __restrict__ counts) {
    int a = blockIdx.x * 256 + threadIdx.x;
    if (a < AN) atomicAdd(&counts[mol_id[a]], 1.f);
}

__global__ __launch_bounds__(256) void k_div(const float* __restrict__ sums,
                                             const float* __restrict__ counts,
                                             float* __restrict__ out) {
    int i = blockIdx.x * 256 + threadIdx.x;
    if (i < NMOL * HD) out[i] = sums[i] / fmaxf(counts[i >> 7], 1.f);
}

extern "C" void kernel_launch(void* const* d_in, const int* in_sizes, int n_in,
                              void* d_out, int out_size, void* d_ws, size_t ws_size,
                              hipStream_t stream) {
    const float* fatoms = (const float*)d_in[0];
    const float* fbonds = (const float*)d_in[1];
    const float* tree   = (const float*)d_in[2];
    const int*   agraph = (const int*)d_in[3];
    const int*   bgraph = (const int*)d_in[4];
    const int*   mol_id = (const int*)d_in[5];
    const float* W_i    = (const float*)d_in[6];
    const float* W_h    = (const float*)d_in[7];
    const float* W_o    = (const float*)d_in[8];
    const float* b_o    = (const float*)d_in[9];
    float* out = (float*)d_out;

    size_t tbl   = (size_t)BN * HD;     // u16 per message table
    size_t treeN = (size_t)MN * HD;     // u16 for tree_bf
    size_t redN  = (size_t)(NMOL * HD + NMOL);

    u16* t0 = (u16*)d_ws;
    u16* t1 = t0 + tbl;

    size_t need_mfma = (2 * tbl + treeN + 2 * BSZ) * 2 + redN * 4;
    size_t need_uni  = (2 * tbl + treeN) * 2 + redN * 4;

    if (ws_size >= need_mfma) {
        u16* tree_bf = t1 + tbl;
        u16* Bit     = tree_bf + treeN;
        u16* Bat     = Bit + BSZ;
        float* sums   = (float*)(Bat + BSZ);
        float* counts = sums + (size_t)NMOL * HD;

        hipMemsetAsync(sums, 0, redN * sizeof(float), stream);
        k_tree<<<(MN * HD / 4) / 256, 256, 0, stream>>>(tree, tree_bf);
        k_prepB<<<(2 * BSZ) / 256, 256, 0, stream>>>(W_h, W_i, W_o, b_o, Bit, Bat);
        k_binput_mfma<<<BN / 64, 256, 0, stream>>>(fbonds, Bit, t0);

        u16* cur = t0;
        u16* nxt = t1;
        for (int it = 0; it < 4; ++it) {
            k_iter_mfma<<<BN / 64, 256, 0, stream>>>(tree_bf, cur, fbonds, bgraph, Bit, nxt);
            u16* t = cur; cur = nxt; nxt = t;
        }
        k_counts<<<(AN + 255) / 256, 256, 0, stream>>>(mol_id, counts);
        k_atom_mfma<<<(AN + 63) / 64, 256, 0, stream>>>(tree_bf, cur, fatoms, agraph,
                                                        mol_id, Bat, sums);
        k_div<<<(NMOL * HD) / 256, 256, 0, stream>>>(sums, counts, out);
    } else {
        bool unified = ws_size >= need_uni;
        u16* tree_bf = unified ? (t1 + tbl) : nullptr;
        float* sums   = (float*)(unified ? (void*)(tree_bf + treeN) : (void*)(t1 + tbl));
        float* counts = sums + (size_t)NMOL * HD;

        hipMemsetAsync(sums, 0, redN * sizeof(float), stream);
        if (unified)
            k_tree<<<(MN * HD / 4) / 256, 256, 0, stream>>>(tree, tree_bf);
        k_binput<<<BN / 16, 256, 0, stream>>>(fbonds, W_i, t0);

        u16* cur = t0;
        u16* nxt = t1;
        for (int it = 0; it < 4; ++it) {
            if (unified)
                k_iter<true><<<BN / 16, 256, 0, stream>>>(tree, tree_bf, cur, fbonds, bgraph, W_h, W_i, nxt);
            else
                k_iter<false><<<BN / 16, 256, 0, stream>>>(tree, tree_bf, cur, fbonds, bgraph, W_h, W_i, nxt);
            u16* t = cur; cur = nxt; nxt = t;
        }
        k_counts<<<(AN + 255) / 256, 256, 0, stream>>>(mol_id, counts);
        if (unified)
            k_atom<true><<<AN / 16, 256, 0, stream>>>(tree, tree_bf, cur, fatoms, agraph, mol_id, W_o, b_o, sums);
        else
            k_atom<false><<<AN / 16, 256, 0, stream>>>(tree, tree_bf, cur, fatoms, agraph, mol_id, W_o, b_o, sums);
        k_div<<<(NMOL * HD) / 256, 256, 0, stream>>>(sums, counts, out);
    }
}